// Round 12
// baseline (244.046 us; speedup 1.0000x reference)
//
#include <hip/hip_runtime.h>
#include <stdint.h>

// Top-K (K=64) per row of [4096, 32768] f32, relu'd, scattered into zeros.
//
// Round-12: single-variable A/B vs R11 — NONTEMPORAL -> REGULAR zero stores.
//   R11 falsified the tail model (brute tail == radix tail == ~223-232us).
//   Every lean fused variant pins at ~4.8 TB/s effective. Suspect: NT 16B
//   stores bypass L2 -> partial-line writes at the DRAM controller ->
//   read-modify-write, ~2x cost on the 537MB write stream. Regular stores
//   fill whole 64B lines in L2 (4 lanes cover a line) and evict as full
//   bursts — the rocclr fill does exactly this at 6.6 TB/s.
//   ONLY change from R11: the 4 zero stores are plain float4 assignments.
//  - Capture (R8, branchless): each thread owns 8 LDS uint2 slots + trash;
//    per element an UNCONDITIONAL ds_write_b64 {key,pos} to slot min(c,8),
//    c += (f >= 2.6f). No branch/atomic/wait in the hot loop.
//  - Tail: compact slots (shfl prefix scan, 3 barriers), then brute-force
//    exact rank over M~153 candidates (one LDS-broadcast loop, no barriers);
//    take iff rank < 64. Exact jax.lax.top_k lowest-index tie-break.
//  - Fallback (slot overflow or M < 64; statistically never): exact 32-bit
//    radix over global re-reads, ordered tie-break, explicit relu.

#define LROW   32768
#define NT     256
#define NWAVE  (NT / 64)            // 4
#define ITERS  (LROW / (NT * 4))    // 32
#define KSEL   64u
#define NSLOT  8                    // {key,pos} slots per thread (+1 trash)
#define FCUT   2.6f                 // candidate threshold (value space)

typedef float vf4 __attribute__((ext_vector_type(4)));

// float bits -> order-preserving uint (used only in the fallback)
__device__ __forceinline__ uint32_t f2o(uint32_t b) {
    return b ^ (uint32_t)(((int32_t)b >> 31) | 0x80000000u);
}
__device__ __forceinline__ float o2f(uint32_t u) {
    uint32_t b = (u & 0x80000000u) ? (u ^ 0x80000000u) : ~u;
    return __uint_as_float(b);
}

// Fallback-only: wave 0 scans hist[nb-1..0] from the top; finds bucket b*
// with cum_before < need <= cum_before + hist[b*]; writes
// {b*, cum_before, hist[b*]} to ctrl[0..2].
__device__ __forceinline__ void wave0_select(uint32_t* ctrl, const uint32_t* hist,
                                             int nb, uint32_t need,
                                             int tid, int lane)
{
    if (tid < 64) {
        uint32_t cum = 0;
        int done = 0;
        for (int base = nb; base > 0 && !done; base -= 64) {
            uint32_t c = hist[base - 1 - lane];   // lane 0 = highest bucket
            uint32_t inc = c;
            #pragma unroll
            for (int off = 1; off < 64; off <<= 1) {
                uint32_t t = __shfl_up(inc, off);
                if (lane >= off) inc += t;
            }
            uint32_t tot = __shfl(inc, 63);
            uint32_t pre = inc - c;
            bool hit = (cum + pre < need) && (cum + pre + c >= need);
            if (hit) {
                ctrl[0] = (uint32_t)(base - 1 - lane);
                ctrl[1] = cum + pre;
                ctrl[2] = c;
            }
            done = (__ballot(hit) != 0ull);
            cum += tot;
        }
    }
}

// Branchless per-element capture: unconditional slot write + cndmask bump.
__device__ __forceinline__ void scan4(const float4& v, int p4, int tid,
                                      uint2* pool, uint32_t& c)
{
    const float f0 = v.x, f1 = v.y, f2 = v.z, f3 = v.w;
    uint32_t s;
    s = (c > (uint32_t)NSLOT) ? (uint32_t)NSLOT : c;
    pool[s * NT + tid] = make_uint2(__float_as_uint(f0), (uint32_t)(p4 * 4 + 0));
    c += (f0 >= FCUT) ? 1u : 0u;
    s = (c > (uint32_t)NSLOT) ? (uint32_t)NSLOT : c;
    pool[s * NT + tid] = make_uint2(__float_as_uint(f1), (uint32_t)(p4 * 4 + 1));
    c += (f1 >= FCUT) ? 1u : 0u;
    s = (c > (uint32_t)NSLOT) ? (uint32_t)NSLOT : c;
    pool[s * NT + tid] = make_uint2(__float_as_uint(f2), (uint32_t)(p4 * 4 + 2));
    c += (f2 >= FCUT) ? 1u : 0u;
    s = (c > (uint32_t)NSLOT) ? (uint32_t)NSLOT : c;
    pool[s * NT + tid] = make_uint2(__float_as_uint(f3), (uint32_t)(p4 * 4 + 3));
    c += (f3 >= FCUT) ? 1u : 0u;
}

__global__ __launch_bounds__(NT, 8) void topk_kernel(
    const float* __restrict__ x, float* __restrict__ out)
{
    // pool: slot view [NSLOT+1][NT] during stream; compacted list + fallback
    // histogram afterwards. (NSLOT+1)*NT uint2 = 18 KiB.
    __shared__ uint2    pool[(NSLOT + 1) * NT];
    __shared__ uint32_t ctrl[64];   // [0..2] fb-select, [8] ovf, [9] M, [16..] wave sums

    const int tid  = threadIdx.x;
    const int lane = tid & 63;
    const int wid  = tid >> 6;
    const size_t rowoff = (size_t)blockIdx.x * LROW;
    const float4* __restrict__ xin  = (const float4*)(x + rowoff);
    vf4*          __restrict__ xout = (vf4*)(out + rowoff);

    if (tid == 0) ctrl[8] = 0u;
    __syncthreads();

    // ---- Phase 0: fused stream: 4 loads | 4 REGULAR zero-stores | capture ----
    uint32_t c = 0;
    const vf4 z = (vf4)(0.0f);
    for (int j = 0; j < ITERS; j += 4) {
        int p0 = (j + 0) * NT + tid;
        int p1 = (j + 1) * NT + tid;
        int p2 = (j + 2) * NT + tid;
        int p3 = (j + 3) * NT + tid;
        float4 v0 = xin[p0];
        float4 v1 = xin[p1];
        float4 v2 = xin[p2];
        float4 v3 = xin[p3];
        xout[p0] = z;                 // regular global_store_dwordx4 (L2-alloc)
        xout[p1] = z;
        xout[p2] = z;
        xout[p3] = z;
        scan4(v0, p0, tid, pool, c);
        scan4(v1, p1, tid, pool, c);
        scan4(v2, p2, tid, pool, c);
        scan4(v3, p3, tid, pool, c);
    }

    // ---- Compact per-thread slots into one list (3 barriers total) ----
    uint32_t cc = (c > (uint32_t)NSLOT) ? (uint32_t)NSLOT : c;
    uint2 mine[NSLOT];
    #pragma unroll
    for (int s = 0; s < NSLOT; ++s) mine[s] = pool[s * NT + tid];  // own slots

    uint32_t inc = cc;
    #pragma unroll
    for (int off = 1; off < 64; off <<= 1) {
        uint32_t t = __shfl_up(inc, off);
        if (lane >= off) inc += t;
    }
    if (lane == 63) ctrl[16 + wid] = inc;
    if (__any(c > (uint32_t)NSLOT) && lane == 0) ctrl[8] = 1u;  // overflow
    __syncthreads();                                   // B1: reads done, sums in
    if (tid < NWAVE) {
        uint32_t v = ctrl[16 + tid];
        uint32_t i2 = v;
        #pragma unroll
        for (int off = 1; off < NWAVE; off <<= 1) {
            uint32_t t = __shfl_up(i2, off);
            if (lane >= off) i2 += t;
        }
        if (tid == NWAVE - 1) ctrl[9] = i2;            // total M
        ctrl[16 + tid] = i2 - v;                       // exclusive wave base
    }
    __syncthreads();                                   // B2
    const uint32_t M   = ctrl[9];
    const bool     ovf = (ctrl[8] != 0u);
    uint32_t ofs = ctrl[16 + wid] + (inc - cc);
    #pragma unroll
    for (int s = 0; s < NSLOT; ++s)
        if ((uint32_t)s < cc) pool[ofs + s] = mine[s];
    __syncthreads();                                   // B3: list ready

    if (!ovf && M >= KSEL) {                           // M <= 2048 structurally
        // ---- Brute-force exact rank (no barriers, all waves parallel) ----
        // rank(i) = #{key_j > key_i} + #{key_j == key_i && pos_j < pos_i};
        // take iff rank < KSEL. Exact jax.lax.top_k (lowest-index ties).
        for (uint32_t i = tid; i < M; i += NT) {
            uint2 me = pool[i];
            uint32_t rank = 0;
            for (uint32_t j2 = 0; j2 < M; ++j2) {
                uint2 oth = pool[j2];                  // LDS broadcast read
                rank += (oth.x > me.x) ||
                        (oth.x == me.x && oth.y < me.y);
            }
            if (rank < KSEL)
                out[rowoff + me.y] = __uint_as_float(me.x);  // >= 2.6 > 0
        }
        return;
    }

    // ---- Fallback: exact 32-bit radix over global re-reads (correctness
    //      insurance; statistically never taken for N(0,1) rows) ----
    uint32_t* hist2 = (uint32_t*)pool;   // 2048-entry histogram (4608 u32 avail)

    // Level A: bits 31:21
    for (int i = tid; i < 2048; i += NT) hist2[i] = 0u;
    __syncthreads();
    for (int j = 0; j < ITERS; ++j) {
        float4 v = xin[j * NT + tid];
        uint32_t u[4] = { f2o(__float_as_uint(v.x)), f2o(__float_as_uint(v.y)),
                          f2o(__float_as_uint(v.z)), f2o(__float_as_uint(v.w)) };
        #pragma unroll
        for (int q = 0; q < 4; ++q) atomicAdd(&hist2[u[q] >> 21], 1u);
    }
    __syncthreads();
    wave0_select(ctrl, hist2, 2048, KSEL, tid, lane);
    __syncthreads();
    uint32_t bA = ctrl[0], cumA = ctrl[1];
    uint32_t needB = KSEL - cumA;

    // Level B: bits 20:10 within bucket bA
    __syncthreads();
    for (int i = tid; i < 2048; i += NT) hist2[i] = 0u;
    __syncthreads();
    for (int j = 0; j < ITERS; ++j) {
        float4 v = xin[j * NT + tid];
        uint32_t u[4] = { f2o(__float_as_uint(v.x)), f2o(__float_as_uint(v.y)),
                          f2o(__float_as_uint(v.z)), f2o(__float_as_uint(v.w)) };
        #pragma unroll
        for (int q = 0; q < 4; ++q)
            if ((u[q] >> 21) == bA) atomicAdd(&hist2[(u[q] >> 10) & 0x7FFu], 1u);
    }
    __syncthreads();
    wave0_select(ctrl, hist2, 2048, needB, tid, lane);
    __syncthreads();
    uint32_t bB = ctrl[0], cumB = ctrl[1];
    uint32_t P22 = (bA << 11) | bB;
    uint32_t needC = needB - cumB;

    // Level C: bits 9:0 within prefix P22
    __syncthreads();
    for (int i = tid; i < 2048; i += NT) hist2[i] = 0u;
    __syncthreads();
    for (int j = 0; j < ITERS; ++j) {
        float4 v = xin[j * NT + tid];
        uint32_t u[4] = { f2o(__float_as_uint(v.x)), f2o(__float_as_uint(v.y)),
                          f2o(__float_as_uint(v.z)), f2o(__float_as_uint(v.w)) };
        #pragma unroll
        for (int q = 0; q < 4; ++q)
            if ((u[q] >> 10) == P22) atomicAdd(&hist2[u[q] & 0x3FFu], 1u);
    }
    __syncthreads();
    wave0_select(ctrl, hist2, 1024, needC, tid, lane);
    __syncthreads();
    uint32_t bC = ctrl[0], cumC = ctrl[1];
    uint32_t T32f = (P22 << 10) | bC;
    uint32_t r2   = needC - cumC;    // #(==T32f) to include, lowest index first

    // Ordered rank of ==T32f over contiguous chunks (index order), then scatter.
    const int cbase = tid * (LROW / NT);
    uint32_t cc2 = 0;
    for (int j = 0; j < LROW / NT; ++j)
        cc2 += (f2o(__float_as_uint(x[rowoff + cbase + j])) == T32f);
    uint32_t inc2 = cc2;
    #pragma unroll
    for (int off = 1; off < 64; off <<= 1) {
        uint32_t t = __shfl_up(inc2, off);
        if (lane >= off) inc2 += t;
    }
    if (lane == 63) ctrl[16 + wid] = inc2;
    __syncthreads();
    if (tid < NWAVE) {
        uint32_t v = ctrl[16 + tid];
        uint32_t i2 = v;
        #pragma unroll
        for (int off = 1; off < NWAVE; off <<= 1) {
            uint32_t t = __shfl_up(i2, off);
            if (lane >= off) i2 += t;
        }
        ctrl[16 + tid] = i2 - v;     // exclusive wave base
    }
    __syncthreads();
    uint32_t rank = ctrl[16 + wid] + (inc2 - cc2);
    for (int j = 0; j < LROW / NT; ++j) {
        uint32_t u = f2o(__float_as_uint(x[rowoff + cbase + j]));
        bool take = false;
        if (u > T32f) take = true;
        else if (u == T32f) { take = (rank < r2); rank++; }
        if (take) {
            float v = o2f(u);
            if (v > 0.f) out[rowoff + cbase + j] = v;   // relu; 0 == background
        }
    }
}

extern "C" void kernel_launch(void* const* d_in, const int* in_sizes, int n_in,
                              void* d_out, int out_size, void* d_ws, size_t ws_size,
                              hipStream_t stream)
{
    const float* x = (const float*)d_in[0];
    float* out = (float*)d_out;
    int rows = in_sizes[0] / LROW;   // 4096

    topk_kernel<<<rows, NT, 0, stream>>>(x, out);
}

// Round 13
// 220.894 us; speedup vs baseline: 1.1048x; 1.1048x over previous
//
#include <hip/hip_runtime.h>
#include <stdint.h>

// Top-K (K=64) per row of [4096, 32768] f32, relu'd, scattered into zeros.
//
// Round-13: R8 base (best, 223.5us) + ONE lever: register-depth pipelining.
//   R12 falsified the NT-store RMW theory (regular stores were WORSE: 244
//   vs 232). All prior levers (capture weight R9, tail algorithm R11, store
//   policy R12, split R5/R7/R10) are individually null or negative.
//   Untested mechanism: __launch_bounds__(256,8) caps VGPRs at 64 ->
//   compiler can't keep more than ~4 float4 loads in flight -> shallow
//   memory clauses. This round: __launch_bounds__(256,4) (128 VGPR cap,
//   16 waves/CU) + 8-deep load batches (32 data VGPRs outstanding).
//  - Capture (R8, branchless): each thread owns 8 LDS uint2 slots + trash;
//    per element an UNCONDITIONAL ds_write_b64 {key,pos} to slot min(c,8),
//    c += (f >= 2.6f). No branch/atomic/wait in the hot loop.
//  - Tail (R8): shfl-prefix compaction, exact 4x8-bit radix select over the
//    M~153 candidates, scatter; ties at the exact 32-bit key included
//    lowest-index-first (matches jax.lax.top_k).
//  - Fallback (slot overflow or M < 64; statistically never): exact 32-bit
//    radix over global re-reads, ordered tie-break, explicit relu.

#define LROW   32768
#define NT     256
#define NWAVE  (NT / 64)            // 4
#define ITERS  (LROW / (NT * 4))    // 32
#define KSEL   64u
#define CAP    2048u                // max candidates (256 thr x 8 slots)
#define NSLOT  8                    // {key,pos} slots per thread (+1 trash)
#define FCUT   2.6f                 // candidate threshold (value space)

typedef float vf4 __attribute__((ext_vector_type(4)));

// float bits -> order-preserving uint (used only in the fallback)
__device__ __forceinline__ uint32_t f2o(uint32_t b) {
    return b ^ (uint32_t)(((int32_t)b >> 31) | 0x80000000u);
}
__device__ __forceinline__ float o2f(uint32_t u) {
    uint32_t b = (u & 0x80000000u) ? (u ^ 0x80000000u) : ~u;
    return __uint_as_float(b);
}

// Wave 0 scans hist[nb-1..0] from the top; finds bucket b* with
// cum_before < need <= cum_before + hist[b*]; writes {b*, cum_before, hist[b*]}
// to ctrl[0..2]. Caller syncs before (hist ready) and after (result visible).
__device__ __forceinline__ void wave0_select(uint32_t* ctrl, const uint32_t* hist,
                                             int nb, uint32_t need,
                                             int tid, int lane)
{
    if (tid < 64) {
        uint32_t cum = 0;
        int done = 0;
        for (int base = nb; base > 0 && !done; base -= 64) {
            uint32_t c = hist[base - 1 - lane];   // lane 0 = highest bucket
            uint32_t inc = c;
            #pragma unroll
            for (int off = 1; off < 64; off <<= 1) {
                uint32_t t = __shfl_up(inc, off);
                if (lane >= off) inc += t;
            }
            uint32_t tot = __shfl(inc, 63);
            uint32_t pre = inc - c;
            bool hit = (cum + pre < need) && (cum + pre + c >= need);
            if (hit) {
                ctrl[0] = (uint32_t)(base - 1 - lane);
                ctrl[1] = cum + pre;
                ctrl[2] = c;
            }
            done = (__ballot(hit) != 0ull);
            cum += tot;
        }
    }
}

// Branchless per-element capture: unconditional slot write + cndmask bump.
__device__ __forceinline__ void scan4(const float4& v, int p4, int tid,
                                      uint2* pool, uint32_t& c)
{
    const float f0 = v.x, f1 = v.y, f2 = v.z, f3 = v.w;
    uint32_t s;
    s = (c > (uint32_t)NSLOT) ? (uint32_t)NSLOT : c;
    pool[s * NT + tid] = make_uint2(__float_as_uint(f0), (uint32_t)(p4 * 4 + 0));
    c += (f0 >= FCUT) ? 1u : 0u;
    s = (c > (uint32_t)NSLOT) ? (uint32_t)NSLOT : c;
    pool[s * NT + tid] = make_uint2(__float_as_uint(f1), (uint32_t)(p4 * 4 + 1));
    c += (f1 >= FCUT) ? 1u : 0u;
    s = (c > (uint32_t)NSLOT) ? (uint32_t)NSLOT : c;
    pool[s * NT + tid] = make_uint2(__float_as_uint(f2), (uint32_t)(p4 * 4 + 2));
    c += (f2 >= FCUT) ? 1u : 0u;
    s = (c > (uint32_t)NSLOT) ? (uint32_t)NSLOT : c;
    pool[s * NT + tid] = make_uint2(__float_as_uint(f3), (uint32_t)(p4 * 4 + 3));
    c += (f3 >= FCUT) ? 1u : 0u;
}

__global__ __launch_bounds__(NT, 4) void topk_kernel(
    const float* __restrict__ x, float* __restrict__ out)
{
    // pool: slot view [NSLOT+1][NT] during stream; list view [CAP] after.
    __shared__ uint2    pool[(NSLOT + 1) * NT];   // 18 KiB
    __shared__ uint32_t hist[256];
    __shared__ uint32_t ctrl[64];   // [0..2] select, [8] ovf, [9] M, [16..] wave sums

    const int tid  = threadIdx.x;
    const int lane = tid & 63;
    const int wid  = tid >> 6;
    const size_t rowoff = (size_t)blockIdx.x * LROW;
    const float4* __restrict__ xin  = (const float4*)(x + rowoff);
    vf4*          __restrict__ xout = (vf4*)(out + rowoff);

    if (tid == 0) ctrl[8] = 0u;
    __syncthreads();

    // ---- Phase 0: 8-deep batches: 8 loads | 8 NT zero-stores | 8 scans ----
    uint32_t c = 0;
    const vf4 z = (vf4)(0.0f);
    for (int j = 0; j < ITERS; j += 8) {
        int p[8];
        float4 v[8];
        #pragma unroll
        for (int b = 0; b < 8; ++b) p[b] = (j + b) * NT + tid;
        #pragma unroll
        for (int b = 0; b < 8; ++b) v[b] = xin[p[b]];       // 8 loads in flight
        #pragma unroll
        for (int b = 0; b < 8; ++b)
            __builtin_nontemporal_store(z, &xout[p[b]]);
        #pragma unroll
        for (int b = 0; b < 8; ++b) scan4(v[b], p[b], tid, pool, c);
    }

    // ---- Compact per-thread slots into one list ----
    uint32_t cc = (c > (uint32_t)NSLOT) ? (uint32_t)NSLOT : c;   // valid slots
    uint2 mine[NSLOT];
    #pragma unroll
    for (int s = 0; s < NSLOT; ++s) mine[s] = pool[s * NT + tid];

    uint32_t inc = cc;
    #pragma unroll
    for (int off = 1; off < 64; off <<= 1) {
        uint32_t t = __shfl_up(inc, off);
        if (lane >= off) inc += t;
    }
    if (lane == 63) ctrl[16 + wid] = inc;
    if (__any(c > (uint32_t)NSLOT) && lane == 0) ctrl[8] = 1u;   // overflow
    __syncthreads();
    if (tid < NWAVE) {
        uint32_t v = ctrl[16 + tid];
        uint32_t i2 = v;
        #pragma unroll
        for (int off = 1; off < NWAVE; off <<= 1) {
            uint32_t t = __shfl_up(i2, off);
            if (lane >= off) i2 += t;
        }
        if (tid == NWAVE - 1) ctrl[9] = i2;          // total M
        ctrl[16 + tid] = i2 - v;                     // exclusive wave base
    }
    __syncthreads();
    const uint32_t M   = ctrl[9];
    const bool     ovf = (ctrl[8] != 0u);
    uint32_t ofs = ctrl[16 + wid] + (inc - cc);
    #pragma unroll
    for (int s = 0; s < NSLOT; ++s)
        if ((uint32_t)s < cc) pool[ofs + s] = mine[s];
    __syncthreads();

    if (!ovf && M >= KSEL && M <= CAP) {
        // ---- Main path: exact 4x8-bit radix select over M candidates ----
        uint32_t need = KSEL;
        uint32_t pref = 0;
        uint32_t cnt  = 0;
        #pragma unroll
        for (int L = 3; L >= 0; --L) {
            __syncthreads();
            if (tid < 256) hist[tid] = 0u;
            __syncthreads();
            for (uint32_t i = tid; i < M; i += NT) {
                uint32_t u = pool[i].x;
                bool inb = (L == 3) || ((u >> ((L + 1) * 8)) == pref);
                if (inb) atomicAdd(&hist[(u >> (L * 8)) & 0xFFu], 1u);
            }
            __syncthreads();
            wave0_select(ctrl, hist, 256, need, tid, lane);
            __syncthreads();
            uint32_t d = ctrl[0], cum = ctrl[1];
            cnt = ctrl[2];
            pref = (pref << 8) | d;
            need = need - cum;        // 1..cnt
        }
        uint32_t T32 = pref;          // exact 64th-largest key (raw bits)
        uint32_t r   = need;          // #(==T32) to include, lowest index first

        // ---- Scatter winners straight from the candidate list ----
        for (uint32_t i = tid; i < M; i += NT) {
            uint32_t u = pool[i].x;
            if (u > T32) {
                out[rowoff + pool[i].y] = __uint_as_float(u);  // >= 2.6 > 0
            } else if (u == T32) {
                bool take = (r == cnt);
                if (!take) {
                    uint32_t myp = pool[i].y, rank = 0;
                    for (uint32_t j2 = 0; j2 < M; ++j2)
                        rank += (pool[j2].x == T32 && pool[j2].y < myp);
                    take = (rank < r);
                }
                if (take) out[rowoff + pool[i].y] = __uint_as_float(u);
            }
        }
        return;
    }

    // ---- Fallback: exact 32-bit radix over global re-reads (correctness
    //      insurance; statistically never taken for N(0,1) rows) ----
    uint32_t* hist2 = (uint32_t*)pool;   // 2048-entry histogram (4608 u32 avail)

    // Level A: bits 31:21
    for (int i = tid; i < 2048; i += NT) hist2[i] = 0u;
    __syncthreads();
    for (int j = 0; j < ITERS; ++j) {
        float4 v = xin[j * NT + tid];
        uint32_t u[4] = { f2o(__float_as_uint(v.x)), f2o(__float_as_uint(v.y)),
                          f2o(__float_as_uint(v.z)), f2o(__float_as_uint(v.w)) };
        #pragma unroll
        for (int q = 0; q < 4; ++q) atomicAdd(&hist2[u[q] >> 21], 1u);
    }
    __syncthreads();
    wave0_select(ctrl, hist2, 2048, KSEL, tid, lane);
    __syncthreads();
    uint32_t bA = ctrl[0], cumA = ctrl[1];
    uint32_t needB = KSEL - cumA;

    // Level B: bits 20:10 within bucket bA
    __syncthreads();
    for (int i = tid; i < 2048; i += NT) hist2[i] = 0u;
    __syncthreads();
    for (int j = 0; j < ITERS; ++j) {
        float4 v = xin[j * NT + tid];
        uint32_t u[4] = { f2o(__float_as_uint(v.x)), f2o(__float_as_uint(v.y)),
                          f2o(__float_as_uint(v.z)), f2o(__float_as_uint(v.w)) };
        #pragma unroll
        for (int q = 0; q < 4; ++q)
            if ((u[q] >> 21) == bA) atomicAdd(&hist2[(u[q] >> 10) & 0x7FFu], 1u);
    }
    __syncthreads();
    wave0_select(ctrl, hist2, 2048, needB, tid, lane);
    __syncthreads();
    uint32_t bB = ctrl[0], cumB = ctrl[1];
    uint32_t P22 = (bA << 11) | bB;
    uint32_t needC = needB - cumB;

    // Level C: bits 9:0 within prefix P22
    __syncthreads();
    for (int i = tid; i < 2048; i += NT) hist2[i] = 0u;
    __syncthreads();
    for (int j = 0; j < ITERS; ++j) {
        float4 v = xin[j * NT + tid];
        uint32_t u[4] = { f2o(__float_as_uint(v.x)), f2o(__float_as_uint(v.y)),
                          f2o(__float_as_uint(v.z)), f2o(__float_as_uint(v.w)) };
        #pragma unroll
        for (int q = 0; q < 4; ++q)
            if ((u[q] >> 10) == P22) atomicAdd(&hist2[u[q] & 0x3FFu], 1u);
    }
    __syncthreads();
    wave0_select(ctrl, hist2, 1024, needC, tid, lane);
    __syncthreads();
    uint32_t bC = ctrl[0], cumC = ctrl[1];
    uint32_t T32f = (P22 << 10) | bC;
    uint32_t r2   = needC - cumC;    // #(==T32f) to include, lowest index first

    // Ordered rank of ==T32f over contiguous chunks (index order), then scatter.
    const int cbase = tid * (LROW / NT);
    uint32_t cc2 = 0;
    for (int j = 0; j < LROW / NT; ++j)
        cc2 += (f2o(__float_as_uint(x[rowoff + cbase + j])) == T32f);
    uint32_t inc2 = cc2;
    #pragma unroll
    for (int off = 1; off < 64; off <<= 1) {
        uint32_t t = __shfl_up(inc2, off);
        if (lane >= off) inc2 += t;
    }
    if (lane == 63) ctrl[16 + wid] = inc2;
    __syncthreads();
    if (tid < NWAVE) {
        uint32_t v = ctrl[16 + tid];
        uint32_t i2 = v;
        #pragma unroll
        for (int off = 1; off < NWAVE; off <<= 1) {
            uint32_t t = __shfl_up(i2, off);
            if (lane >= off) i2 += t;
        }
        ctrl[16 + tid] = i2 - v;     // exclusive wave base
    }
    __syncthreads();
    uint32_t rank = ctrl[16 + wid] + (inc2 - cc2);
    for (int j = 0; j < LROW / NT; ++j) {
        uint32_t u = f2o(__float_as_uint(x[rowoff + cbase + j]));
        bool take = false;
        if (u > T32f) take = true;
        else if (u == T32f) { take = (rank < r2); rank++; }
        if (take) {
            float v = o2f(u);
            if (v > 0.f) out[rowoff + cbase + j] = v;   // relu; 0 == background
        }
    }
}

extern "C" void kernel_launch(void* const* d_in, const int* in_sizes, int n_in,
                              void* d_out, int out_size, void* d_ws, size_t ws_size,
                              hipStream_t stream)
{
    const float* x = (const float*)d_in[0];
    float* out = (float*)d_out;
    int rows = in_sizes[0] / LROW;   // 4096

    topk_kernel<<<rows, NT, 0, stream>>>(x, out);
}